// Round 8
// baseline (171.712 us; speedup 1.0000x reference)
//
#include <hip/hip_runtime.h>

#define BATCH   8
#define SEQLEN  2048
#define DMODEL  1024
#define DSTATE  16
#define BLOCK   256
#define LOG2E   1.4426950408889634f

// ---------------------------------------------------------------------------
// Phase A: per-(b,d,chunk) local scan from h=0. B tile in LDS (2 KB).
// u/delta: depth-4 register prefetch, pinned with empty inline-asm so the
// compiler cannot sink the loads to their uses (R5 failure mode).
// ws writes are non-temporal (keep L3 for u/delta). Emits h_loc[16]+dsum.
// ---------------------------------------------------------------------------
template<int NC>
__global__ __launch_bounds__(BLOCK, 8) void ssm_phaseA(
    const float* __restrict__ u,  const float* __restrict__ de,
    const float* __restrict__ A,  const float* __restrict__ Bm,
    float* __restrict__ ws_h, float* __restrict__ ws_d)
{
    constexpr int TC = SEQLEN / NC;
    __shared__ __align__(16) float sB[TC * DSTATE];
    const int tid = threadIdx.x;
    const int d   = blockIdx.x * BLOCK + tid;
    const int c   = blockIdx.y;
    const int b   = blockIdx.z;
    const int t0  = c * TC;

    for (int i = tid; i < TC * DSTATE / 4; i += BLOCK)
        ((float4*)sB)[i] =
            ((const float4*)(Bm + (size_t)(b * SEQLEN + t0) * DSTATE))[i];

    float A2[DSTATE];
    #pragma unroll
    for (int n = 0; n < DSTATE; n += 4) {
        float4 a4 = *(const float4*)(A + (size_t)d * DSTATE + n);
        A2[n+0] = a4.x * LOG2E; A2[n+1] = a4.y * LOG2E;
        A2[n+2] = a4.z * LOG2E; A2[n+3] = a4.w * LOG2E;
    }
    float h[DSTATE];
    #pragma unroll
    for (int n = 0; n < DSTATE; ++n) h[n] = 0.f;
    float dsum = 0.f;

    const float* up = u  + (size_t)(b * SEQLEN + t0) * DMODEL + d;
    const float* dp = de + (size_t)(b * SEQLEN + t0) * DMODEL + d;

    __syncthreads();

    float uf[4], df[4];
    #pragma unroll
    for (int k = 0; k < 4; ++k) {
        uf[k] = up[(size_t)k * DMODEL];
        df[k] = dp[(size_t)k * DMODEL];
    }
    #pragma unroll
    for (int k = 0; k < 4; ++k)
        asm volatile("" : "+v"(uf[k]), "+v"(df[k]));   // pin: loads issue here

    #pragma unroll
    for (int g = 0; g < TC / 4; ++g) {
        float un[4], dn[4];
        if (g + 1 < TC / 4) {
            #pragma unroll
            for (int k = 0; k < 4; ++k) {
                un[k] = up[(size_t)((g+1)*4 + k) * DMODEL];
                dn[k] = dp[(size_t)((g+1)*4 + k) * DMODEL];
            }
            #pragma unroll
            for (int k = 0; k < 4; ++k)
                asm volatile("" : "+v"(un[k]), "+v"(dn[k]));
        }
        #pragma unroll
        for (int k = 0; k < 4; ++k) {
            const int t = g * 4 + k;
            const float dl = df[k], uu = uf[k];
            dsum += dl;
            const float du = dl * uu;
            #pragma unroll
            for (int n = 0; n < DSTATE; n += 4) {
                float4 b4 = *(const float4*)(sB + t * DSTATE + n);
                h[n+0] = __builtin_amdgcn_exp2f(dl * A2[n+0]) * h[n+0] + du * b4.x;
                h[n+1] = __builtin_amdgcn_exp2f(dl * A2[n+1]) * h[n+1] + du * b4.y;
                h[n+2] = __builtin_amdgcn_exp2f(dl * A2[n+2]) * h[n+2] + du * b4.z;
                h[n+3] = __builtin_amdgcn_exp2f(dl * A2[n+3]) * h[n+3] + du * b4.w;
            }
        }
        if (g + 1 < TC / 4) {
            #pragma unroll
            for (int k = 0; k < 4; ++k) { uf[k] = un[k]; df[k] = dn[k]; }
        }
    }

    float* wh = ws_h + (size_t)(b * NC + c) * DSTATE * DMODEL + d;
    #pragma unroll
    for (int n = 0; n < DSTATE; ++n)
        __builtin_nontemporal_store(h[n], wh + (size_t)n * DMODEL);
    __builtin_nontemporal_store(dsum, ws_d + (size_t)(b * NC + c) * DMODEL + d);
}

// ---------------------------------------------------------------------------
// Phase B: inter-chunk exclusive prefix scan, in place. Non-temporal ws
// traffic (don't evict u/delta from L3).
// ---------------------------------------------------------------------------
template<int NC>
__global__ __launch_bounds__(BLOCK) void ssm_phaseB(
    const float* __restrict__ A,
    float* __restrict__ ws_h, const float* __restrict__ ws_d)
{
    const int gid = blockIdx.x * BLOCK + threadIdx.x;   // (b, n, d)
    const int d  = gid % DMODEL;
    const int bn = gid / DMODEL;
    const int n  = bn % DSTATE;
    const int b  = bn / DSTATE;

    const float a2 = A[(size_t)d * DSTATE + n] * LOG2E;
    float h = 0.f;
    size_t ih = (size_t)b * NC * DSTATE * DMODEL + (size_t)n * DMODEL + d;
    size_t id = (size_t)b * NC * DMODEL + d;

    #pragma unroll 4
    for (int c = 0; c < NC; ++c) {
        float hl = __builtin_nontemporal_load(ws_h + ih);
        float ds = __builtin_nontemporal_load(ws_d + id);
        __builtin_nontemporal_store(h, ws_h + ih);      // exclusive prefix
        h = __builtin_amdgcn_exp2f(a2 * ds) * h + hl;
        ih += (size_t)DSTATE * DMODEL;
        id += DMODEL;
    }
}

// ---------------------------------------------------------------------------
// Phase C: load incoming state (non-temporal), re-scan chunk, write y
// (non-temporal). B and C tiles in LDS; pinned depth-4 u/delta prefetch.
// ---------------------------------------------------------------------------
template<int NC>
__global__ __launch_bounds__(BLOCK, 7) void ssm_phaseC(
    const float* __restrict__ u,  const float* __restrict__ de,
    const float* __restrict__ A,  const float* __restrict__ Bm,
    const float* __restrict__ Cm, const float* __restrict__ Dv,
    const float* __restrict__ ws_h, float* __restrict__ y)
{
    constexpr int TC = SEQLEN / NC;
    __shared__ __align__(16) float sB[TC * DSTATE];
    __shared__ __align__(16) float sC[TC * DSTATE];
    const int tid = threadIdx.x;
    const int d   = blockIdx.x * BLOCK + tid;
    const int c   = blockIdx.y;
    const int b   = blockIdx.z;
    const int t0  = c * TC;

    for (int i = tid; i < TC * DSTATE / 4; i += BLOCK)
        ((float4*)sB)[i] =
            ((const float4*)(Bm + (size_t)(b * SEQLEN + t0) * DSTATE))[i];
    for (int i = tid; i < TC * DSTATE / 4; i += BLOCK)
        ((float4*)sC)[i] =
            ((const float4*)(Cm + (size_t)(b * SEQLEN + t0) * DSTATE))[i];

    float A2[DSTATE];
    #pragma unroll
    for (int n = 0; n < DSTATE; n += 4) {
        float4 a4 = *(const float4*)(A + (size_t)d * DSTATE + n);
        A2[n+0] = a4.x * LOG2E; A2[n+1] = a4.y * LOG2E;
        A2[n+2] = a4.z * LOG2E; A2[n+3] = a4.w * LOG2E;
    }

    float h[DSTATE];
    {
        const float* wh = ws_h + (size_t)(b * NC + c) * DSTATE * DMODEL + d;
        #pragma unroll
        for (int n = 0; n < DSTATE; ++n)
            h[n] = __builtin_nontemporal_load(wh + (size_t)n * DMODEL);
    }
    const float Dd = Dv[d];
    const float* up = u  + (size_t)(b * SEQLEN + t0) * DMODEL + d;
    const float* dp = de + (size_t)(b * SEQLEN + t0) * DMODEL + d;
    float* yp = y + (size_t)(b * SEQLEN + t0) * DMODEL + d;

    __syncthreads();

    float uf[4], df[4];
    #pragma unroll
    for (int k = 0; k < 4; ++k) {
        uf[k] = up[(size_t)k * DMODEL];
        df[k] = dp[(size_t)k * DMODEL];
    }
    #pragma unroll
    for (int k = 0; k < 4; ++k)
        asm volatile("" : "+v"(uf[k]), "+v"(df[k]));

    #pragma unroll
    for (int g = 0; g < TC / 4; ++g) {
        float un[4], dn[4];
        if (g + 1 < TC / 4) {
            #pragma unroll
            for (int k = 0; k < 4; ++k) {
                un[k] = up[(size_t)((g+1)*4 + k) * DMODEL];
                dn[k] = dp[(size_t)((g+1)*4 + k) * DMODEL];
            }
            #pragma unroll
            for (int k = 0; k < 4; ++k)
                asm volatile("" : "+v"(un[k]), "+v"(dn[k]));
        }
        #pragma unroll
        for (int k = 0; k < 4; ++k) {
            const int t = g * 4 + k;
            const float dl = df[k], uu = uf[k];
            const float du = dl * uu;
            float acc = Dd * uu;
            #pragma unroll
            for (int n = 0; n < DSTATE; n += 4) {
                float4 b4 = *(const float4*)(sB + t * DSTATE + n);
                float4 c4 = *(const float4*)(sC + t * DSTATE + n);
                h[n+0] = __builtin_amdgcn_exp2f(dl * A2[n+0]) * h[n+0] + du * b4.x;
                h[n+1] = __builtin_amdgcn_exp2f(dl * A2[n+1]) * h[n+1] + du * b4.y;
                h[n+2] = __builtin_amdgcn_exp2f(dl * A2[n+2]) * h[n+2] + du * b4.z;
                h[n+3] = __builtin_amdgcn_exp2f(dl * A2[n+3]) * h[n+3] + du * b4.w;
                acc += h[n+0] * c4.x; acc += h[n+1] * c4.y;
                acc += h[n+2] * c4.z; acc += h[n+3] * c4.w;
            }
            __builtin_nontemporal_store(acc, yp + (size_t)t * DMODEL);
        }
        if (g + 1 < TC / 4) {
            #pragma unroll
            for (int k = 0; k < 4; ++k) { uf[k] = un[k]; df[k] = dn[k]; }
        }
    }
}

// ---------------------------------------------------------------------------
// Fallback: 1 thread per (b,d), full sequential scan. Correct but slow.
// ---------------------------------------------------------------------------
__global__ __launch_bounds__(BLOCK) void ssm_naive(
    const float* __restrict__ u,  const float* __restrict__ de,
    const float* __restrict__ A,  const float* __restrict__ Bm,
    const float* __restrict__ Cm, const float* __restrict__ Dv,
    float* __restrict__ y)
{
    const int tid = threadIdx.x;
    const int d   = blockIdx.x * BLOCK + tid;
    const int b   = blockIdx.z;

    float A2[DSTATE];
    #pragma unroll
    for (int n = 0; n < DSTATE; n += 4) {
        float4 a4 = *(const float4*)(A + (size_t)d * DSTATE + n);
        A2[n+0] = a4.x * LOG2E; A2[n+1] = a4.y * LOG2E;
        A2[n+2] = a4.z * LOG2E; A2[n+3] = a4.w * LOG2E;
    }
    float h[DSTATE];
    #pragma unroll
    for (int n = 0; n < DSTATE; ++n) h[n] = 0.f;
    const float Dd = Dv[d];

    const float* up = u  + (size_t)b * SEQLEN * DMODEL + d;
    const float* dp = de + (size_t)b * SEQLEN * DMODEL + d;
    float* yp = y + (size_t)b * SEQLEN * DMODEL + d;

    for (int t = 0; t < SEQLEN; ++t) {
        float dl = dp[(size_t)t * DMODEL];
        float uu = up[(size_t)t * DMODEL];
        float du  = dl * uu;
        float acc = Dd * uu;
        const float* bp = Bm + (size_t)(b * SEQLEN + t) * DSTATE;
        const float* cp = Cm + (size_t)(b * SEQLEN + t) * DSTATE;
        #pragma unroll
        for (int n = 0; n < DSTATE; n += 4) {
            float4 b4 = *(const float4*)(bp + n);
            float4 c4 = *(const float4*)(cp + n);
            h[n+0] = __builtin_amdgcn_exp2f(dl * A2[n+0]) * h[n+0] + du * b4.x;
            h[n+1] = __builtin_amdgcn_exp2f(dl * A2[n+1]) * h[n+1] + du * b4.y;
            h[n+2] = __builtin_amdgcn_exp2f(dl * A2[n+2]) * h[n+2] + du * b4.z;
            h[n+3] = __builtin_amdgcn_exp2f(dl * A2[n+3]) * h[n+3] + du * b4.w;
            acc += h[n+0] * c4.x;
            acc += h[n+1] * c4.y;
            acc += h[n+2] * c4.z;
            acc += h[n+3] * c4.w;
        }
        yp[(size_t)t * DMODEL] = acc;
    }
}

template<int NC>
static void launch_chunked(const float* u, const float* de, const float* A,
                           const float* Bm, const float* Cm, const float* Dv,
                           float* ws, float* y, hipStream_t stream) {
    float* ws_h = ws;
    float* ws_d = ws_h + (size_t)BATCH * NC * DSTATE * DMODEL;
    dim3 grid(DMODEL / BLOCK, NC, BATCH);
    ssm_phaseA<NC><<<grid, BLOCK, 0, stream>>>(u, de, A, Bm, ws_h, ws_d);
    dim3 gridB((BATCH * DSTATE * DMODEL) / BLOCK, 1, 1);
    ssm_phaseB<NC><<<gridB, BLOCK, 0, stream>>>(A, ws_h, ws_d);
    ssm_phaseC<NC><<<grid, BLOCK, 0, stream>>>(u, de, A, Bm, Cm, Dv, ws_h, y);
}

extern "C" void kernel_launch(void* const* d_in, const int* in_sizes, int n_in,
                              void* d_out, int out_size, void* d_ws, size_t ws_size,
                              hipStream_t stream) {
    const float* u  = (const float*)d_in[0];
    const float* de = (const float*)d_in[1];
    const float* A  = (const float*)d_in[2];
    const float* Bm = (const float*)d_in[3];
    const float* Cm = (const float*)d_in[4];
    const float* Dv = (const float*)d_in[5];
    float* y = (float*)d_out;

    auto need = [](int nc) {
        return ((size_t)BATCH * nc * DSTATE * DMODEL +
                (size_t)BATCH * nc * DMODEL) * sizeof(float);
    };

    if (ws_size >= need(64)) {
        launch_chunked<64>(u, de, A, Bm, Cm, Dv, (float*)d_ws, y, stream);
    } else if (ws_size >= need(16)) {
        launch_chunked<16>(u, de, A, Bm, Cm, Dv, (float*)d_ws, y, stream);
    } else {
        dim3 grid(DMODEL / BLOCK, 1, BATCH);
        ssm_naive<<<grid, BLOCK, 0, stream>>>(u, de, A, Bm, Cm, Dv, y);
    }
}

// Round 9
// 119.316 us; speedup vs baseline: 1.4391x; 1.4391x over previous
//
#include <hip/hip_runtime.h>

#define BATCH   8
#define SEQLEN  2048
#define DMODEL  1024
#define DSTATE  16
#define BLOCK   256
#define LOG2E   1.4426950408889634f

// ---------------------------------------------------------------------------
// Phase A (dual-chunk ILP): each thread runs TWO independent chunk scans
// (c and c+NC/2) interleaved -> guaranteed 2-way ILP inside each wave.
// NC=128, TC=16. B tiles for both chunks in LDS. No non-temporal.
// ---------------------------------------------------------------------------
template<int NC>
__global__ __launch_bounds__(BLOCK, 4) void ssm_phaseA_dual(
    const float* __restrict__ u,  const float* __restrict__ de,
    const float* __restrict__ A,  const float* __restrict__ Bm,
    float* __restrict__ ws_h, float* __restrict__ ws_d)
{
    constexpr int TC = SEQLEN / NC;
    constexpr int HC = NC / 2;
    __shared__ __align__(16) float sB0[TC * DSTATE];
    __shared__ __align__(16) float sB1[TC * DSTATE];
    const int tid = threadIdx.x;
    const int d   = blockIdx.x * BLOCK + tid;
    const int c0  = blockIdx.y;          // 0..HC-1
    const int c1  = c0 + HC;
    const int b   = blockIdx.z;
    const int t00 = c0 * TC;
    const int t01 = c1 * TC;

    if (tid < TC * DSTATE / 4)
        ((float4*)sB0)[tid] =
            ((const float4*)(Bm + (size_t)(b * SEQLEN + t00) * DSTATE))[tid];
    else if (tid < 2 * (TC * DSTATE / 4))
        ((float4*)sB1)[tid - TC*DSTATE/4] =
            ((const float4*)(Bm + (size_t)(b * SEQLEN + t01) * DSTATE))[tid - TC*DSTATE/4];

    float A2[DSTATE];
    #pragma unroll
    for (int n = 0; n < DSTATE; n += 4) {
        float4 a4 = *(const float4*)(A + (size_t)d * DSTATE + n);
        A2[n+0] = a4.x * LOG2E; A2[n+1] = a4.y * LOG2E;
        A2[n+2] = a4.z * LOG2E; A2[n+3] = a4.w * LOG2E;
    }
    float hA[DSTATE], hB[DSTATE];
    #pragma unroll
    for (int n = 0; n < DSTATE; ++n) { hA[n] = 0.f; hB[n] = 0.f; }
    float dsumA = 0.f, dsumB = 0.f;

    const float* upA = u  + (size_t)(b * SEQLEN + t00) * DMODEL + d;
    const float* dpA = de + (size_t)(b * SEQLEN + t00) * DMODEL + d;
    const float* upB = u  + (size_t)(b * SEQLEN + t01) * DMODEL + d;
    const float* dpB = de + (size_t)(b * SEQLEN + t01) * DMODEL + d;

    __syncthreads();

    float uA0 = upA[0], dA0 = dpA[0], uA1 = upA[DMODEL], dA1 = dpA[DMODEL];
    float uB0 = upB[0], dB0 = dpB[0], uB1 = upB[DMODEL], dB1 = dpB[DMODEL];

    #pragma unroll
    for (int t = 0; t < TC; t += 2) {
        const int i2 = (t + 2 < TC) ? (t + 2) : (TC - 1);
        const int i3 = (t + 3 < TC) ? (t + 3) : (TC - 1);
        float uA2 = upA[(size_t)i2 * DMODEL], dA2 = dpA[(size_t)i2 * DMODEL];
        float uA3 = upA[(size_t)i3 * DMODEL], dA3 = dpA[(size_t)i3 * DMODEL];
        float uB2 = upB[(size_t)i2 * DMODEL], dB2 = dpB[(size_t)i2 * DMODEL];
        float uB3 = upB[(size_t)i3 * DMODEL], dB3 = dpB[(size_t)i3 * DMODEL];

        {   // step t: both chunks interleaved
            dsumA += dA0; dsumB += dB0;
            const float duA = dA0 * uA0, duB = dB0 * uB0;
            #pragma unroll
            for (int n = 0; n < DSTATE; n += 4) {
                float4 b4A = *(const float4*)(sB0 + t * DSTATE + n);
                float4 b4B = *(const float4*)(sB1 + t * DSTATE + n);
                hA[n+0] = __builtin_amdgcn_exp2f(dA0 * A2[n+0]) * hA[n+0] + duA * b4A.x;
                hB[n+0] = __builtin_amdgcn_exp2f(dB0 * A2[n+0]) * hB[n+0] + duB * b4B.x;
                hA[n+1] = __builtin_amdgcn_exp2f(dA0 * A2[n+1]) * hA[n+1] + duA * b4A.y;
                hB[n+1] = __builtin_amdgcn_exp2f(dB0 * A2[n+1]) * hB[n+1] + duB * b4B.y;
                hA[n+2] = __builtin_amdgcn_exp2f(dA0 * A2[n+2]) * hA[n+2] + duA * b4A.z;
                hB[n+2] = __builtin_amdgcn_exp2f(dB0 * A2[n+2]) * hB[n+2] + duB * b4B.z;
                hA[n+3] = __builtin_amdgcn_exp2f(dA0 * A2[n+3]) * hA[n+3] + duA * b4A.w;
                hB[n+3] = __builtin_amdgcn_exp2f(dB0 * A2[n+3]) * hB[n+3] + duB * b4B.w;
            }
        }
        {   // step t+1
            dsumA += dA1; dsumB += dB1;
            const float duA = dA1 * uA1, duB = dB1 * uB1;
            #pragma unroll
            for (int n = 0; n < DSTATE; n += 4) {
                float4 b4A = *(const float4*)(sB0 + (t+1) * DSTATE + n);
                float4 b4B = *(const float4*)(sB1 + (t+1) * DSTATE + n);
                hA[n+0] = __builtin_amdgcn_exp2f(dA1 * A2[n+0]) * hA[n+0] + duA * b4A.x;
                hB[n+0] = __builtin_amdgcn_exp2f(dB1 * A2[n+0]) * hB[n+0] + duB * b4B.x;
                hA[n+1] = __builtin_amdgcn_exp2f(dA1 * A2[n+1]) * hA[n+1] + duA * b4A.y;
                hB[n+1] = __builtin_amdgcn_exp2f(dB1 * A2[n+1]) * hB[n+1] + duB * b4B.y;
                hA[n+2] = __builtin_amdgcn_exp2f(dA1 * A2[n+2]) * hA[n+2] + duA * b4A.z;
                hB[n+2] = __builtin_amdgcn_exp2f(dB1 * A2[n+2]) * hB[n+2] + duB * b4B.z;
                hA[n+3] = __builtin_amdgcn_exp2f(dA1 * A2[n+3]) * hA[n+3] + duA * b4A.w;
                hB[n+3] = __builtin_amdgcn_exp2f(dB1 * A2[n+3]) * hB[n+3] + duB * b4B.w;
            }
        }
        uA0 = uA2; dA0 = dA2; uA1 = uA3; dA1 = dA3;
        uB0 = uB2; dB0 = dB2; uB1 = uB3; dB1 = dB3;
    }

    float* whA = ws_h + (size_t)(b * NC + c0) * DSTATE * DMODEL + d;
    float* whB = ws_h + (size_t)(b * NC + c1) * DSTATE * DMODEL + d;
    #pragma unroll
    for (int n = 0; n < DSTATE; ++n) {
        whA[(size_t)n * DMODEL] = hA[n];
        whB[(size_t)n * DMODEL] = hB[n];
    }
    ws_d[(size_t)(b * NC + c0) * DMODEL + d] = dsumA;
    ws_d[(size_t)(b * NC + c1) * DMODEL + d] = dsumB;
}

// ---------------------------------------------------------------------------
// Phase A (single-chunk, fallback path for NC=64)
// ---------------------------------------------------------------------------
template<int NC>
__global__ __launch_bounds__(BLOCK, 8) void ssm_phaseA_single(
    const float* __restrict__ u,  const float* __restrict__ de,
    const float* __restrict__ A,  const float* __restrict__ Bm,
    float* __restrict__ ws_h, float* __restrict__ ws_d)
{
    constexpr int TC = SEQLEN / NC;
    __shared__ __align__(16) float sB[TC * DSTATE];
    const int tid = threadIdx.x;
    const int d   = blockIdx.x * BLOCK + tid;
    const int c   = blockIdx.y;
    const int b   = blockIdx.z;
    const int t0  = c * TC;

    for (int i = tid; i < TC * DSTATE / 4; i += BLOCK)
        ((float4*)sB)[i] =
            ((const float4*)(Bm + (size_t)(b * SEQLEN + t0) * DSTATE))[i];

    float A2[DSTATE];
    #pragma unroll
    for (int n = 0; n < DSTATE; n += 4) {
        float4 a4 = *(const float4*)(A + (size_t)d * DSTATE + n);
        A2[n+0] = a4.x * LOG2E; A2[n+1] = a4.y * LOG2E;
        A2[n+2] = a4.z * LOG2E; A2[n+3] = a4.w * LOG2E;
    }
    float h[DSTATE];
    #pragma unroll
    for (int n = 0; n < DSTATE; ++n) h[n] = 0.f;
    float dsum = 0.f;

    const float* up = u  + (size_t)(b * SEQLEN + t0) * DMODEL + d;
    const float* dp = de + (size_t)(b * SEQLEN + t0) * DMODEL + d;

    __syncthreads();

    float u0 = up[0], d0 = dp[0];
    float u1 = up[DMODEL], d1 = dp[DMODEL];

    #pragma unroll
    for (int t = 0; t < TC; t += 2) {
        const int i2 = (t + 2 < TC) ? (t + 2) : (TC - 1);
        const int i3 = (t + 3 < TC) ? (t + 3) : (TC - 1);
        float u2 = up[(size_t)i2 * DMODEL], d2 = dp[(size_t)i2 * DMODEL];
        float u3 = up[(size_t)i3 * DMODEL], d3 = dp[(size_t)i3 * DMODEL];
        {
            dsum += d0;
            const float du = d0 * u0;
            #pragma unroll
            for (int n = 0; n < DSTATE; n += 4) {
                float4 b4 = *(const float4*)(sB + t * DSTATE + n);
                h[n+0] = __builtin_amdgcn_exp2f(d0 * A2[n+0]) * h[n+0] + du * b4.x;
                h[n+1] = __builtin_amdgcn_exp2f(d0 * A2[n+1]) * h[n+1] + du * b4.y;
                h[n+2] = __builtin_amdgcn_exp2f(d0 * A2[n+2]) * h[n+2] + du * b4.z;
                h[n+3] = __builtin_amdgcn_exp2f(d0 * A2[n+3]) * h[n+3] + du * b4.w;
            }
        }
        {
            dsum += d1;
            const float du = d1 * u1;
            #pragma unroll
            for (int n = 0; n < DSTATE; n += 4) {
                float4 b4 = *(const float4*)(sB + (t+1) * DSTATE + n);
                h[n+0] = __builtin_amdgcn_exp2f(d1 * A2[n+0]) * h[n+0] + du * b4.x;
                h[n+1] = __builtin_amdgcn_exp2f(d1 * A2[n+1]) * h[n+1] + du * b4.y;
                h[n+2] = __builtin_amdgcn_exp2f(d1 * A2[n+2]) * h[n+2] + du * b4.z;
                h[n+3] = __builtin_amdgcn_exp2f(d1 * A2[n+3]) * h[n+3] + du * b4.w;
            }
        }
        u0 = u2; d0 = d2; u1 = u3; d1 = d3;
    }

    float* wh = ws_h + (size_t)(b * NC + c) * DSTATE * DMODEL + d;
    #pragma unroll
    for (int n = 0; n < DSTATE; ++n) wh[(size_t)n * DMODEL] = h[n];
    ws_d[(size_t)(b * NC + c) * DMODEL + d] = dsum;
}

// ---------------------------------------------------------------------------
// Phase B: inter-chunk exclusive prefix scan, in place (plain loads/stores).
// ---------------------------------------------------------------------------
template<int NC>
__global__ __launch_bounds__(BLOCK) void ssm_phaseB(
    const float* __restrict__ A,
    float* __restrict__ ws_h, const float* __restrict__ ws_d)
{
    const int gid = blockIdx.x * BLOCK + threadIdx.x;   // (b, n, d)
    const int d  = gid % DMODEL;
    const int bn = gid / DMODEL;
    const int n  = bn % DSTATE;
    const int b  = bn / DSTATE;

    const float a2 = A[(size_t)d * DSTATE + n] * LOG2E;
    float h = 0.f;
    size_t ih = (size_t)b * NC * DSTATE * DMODEL + (size_t)n * DMODEL + d;
    size_t id = (size_t)b * NC * DMODEL + d;

    #pragma unroll 4
    for (int c = 0; c < NC; ++c) {
        float hl = ws_h[ih];
        float ds = ws_d[id];
        ws_h[ih] = h;                       // exclusive prefix
        h = __builtin_amdgcn_exp2f(a2 * ds) * h + hl;
        ih += (size_t)DSTATE * DMODEL;
        id += DMODEL;
    }
}

// ---------------------------------------------------------------------------
// Phase C (R7 measured-best): LDS slabs for u/delta + B/C tiles; re-scan
// chunk; y store non-temporal (write-once stream).
// ---------------------------------------------------------------------------
template<int NC>
__global__ __launch_bounds__(BLOCK, 4) void ssm_phaseC(
    const float* __restrict__ u,  const float* __restrict__ de,
    const float* __restrict__ A,  const float* __restrict__ Bm,
    const float* __restrict__ Cm, const float* __restrict__ Dv,
    const float* __restrict__ ws_h, float* __restrict__ y)
{
    constexpr int TC = SEQLEN / NC;
    __shared__ __align__(16) float sB[TC * DSTATE];
    __shared__ __align__(16) float sC[TC * DSTATE];
    __shared__ __align__(16) float sU[TC][BLOCK];
    __shared__ __align__(16) float sD[TC][BLOCK];
    const int tid = threadIdx.x;
    const int d   = blockIdx.x * BLOCK + tid;
    const int c   = blockIdx.y;
    const int b   = blockIdx.z;
    const int t0  = c * TC;
    const int d0b = blockIdx.x * BLOCK;

    if (tid < TC * DSTATE / 4)
        ((float4*)sB)[tid] =
            ((const float4*)(Bm + (size_t)(b * SEQLEN + t0) * DSTATE))[tid];
    else if (tid < 2 * (TC * DSTATE / 4))
        ((float4*)sC)[tid - TC*DSTATE/4] =
            ((const float4*)(Cm + (size_t)(b * SEQLEN + t0) * DSTATE))[tid - TC*DSTATE/4];

    {
        const int tr = tid >> 6, c4 = tid & 63;
        #pragma unroll
        for (int k = 0; k < TC; k += 4) {
            ((float4*)&sU[k + tr][0])[c4] =
                ((const float4*)(u  + (size_t)(b * SEQLEN + t0 + k + tr) * DMODEL + d0b))[c4];
            ((float4*)&sD[k + tr][0])[c4] =
                ((const float4*)(de + (size_t)(b * SEQLEN + t0 + k + tr) * DMODEL + d0b))[c4];
        }
    }

    float A2[DSTATE];
    #pragma unroll
    for (int n = 0; n < DSTATE; n += 4) {
        float4 a4 = *(const float4*)(A + (size_t)d * DSTATE + n);
        A2[n+0] = a4.x * LOG2E; A2[n+1] = a4.y * LOG2E;
        A2[n+2] = a4.z * LOG2E; A2[n+3] = a4.w * LOG2E;
    }

    float h[DSTATE];
    {
        const float* wh = ws_h + (size_t)(b * NC + c) * DSTATE * DMODEL + d;
        #pragma unroll
        for (int n = 0; n < DSTATE; ++n) h[n] = wh[(size_t)n * DMODEL];
    }
    const float Dd = Dv[d];
    float* yp = y + (size_t)(b * SEQLEN + t0) * DMODEL + d;

    __syncthreads();

    #pragma unroll
    for (int t = 0; t < TC; ++t) {
        const float dl = sD[t][tid];
        const float uu = sU[t][tid];
        const float du = dl * uu;
        float acc = Dd * uu;
        #pragma unroll
        for (int n = 0; n < DSTATE; n += 4) {
            float4 b4 = *(const float4*)(sB + t * DSTATE + n);
            float4 c4 = *(const float4*)(sC + t * DSTATE + n);
            h[n+0] = __builtin_amdgcn_exp2f(dl * A2[n+0]) * h[n+0] + du * b4.x;
            h[n+1] = __builtin_amdgcn_exp2f(dl * A2[n+1]) * h[n+1] + du * b4.y;
            h[n+2] = __builtin_amdgcn_exp2f(dl * A2[n+2]) * h[n+2] + du * b4.z;
            h[n+3] = __builtin_amdgcn_exp2f(dl * A2[n+3]) * h[n+3] + du * b4.w;
            acc += h[n+0] * c4.x; acc += h[n+1] * c4.y;
            acc += h[n+2] * c4.z; acc += h[n+3] * c4.w;
        }
        __builtin_nontemporal_store(acc, yp + (size_t)t * DMODEL);
    }
}

// ---------------------------------------------------------------------------
// Fallback: 1 thread per (b,d), full sequential scan. Correct but slow.
// ---------------------------------------------------------------------------
__global__ __launch_bounds__(BLOCK) void ssm_naive(
    const float* __restrict__ u,  const float* __restrict__ de,
    const float* __restrict__ A,  const float* __restrict__ Bm,
    const float* __restrict__ Cm, const float* __restrict__ Dv,
    float* __restrict__ y)
{
    const int tid = threadIdx.x;
    const int d   = blockIdx.x * BLOCK + tid;
    const int b   = blockIdx.z;

    float A2[DSTATE];
    #pragma unroll
    for (int n = 0; n < DSTATE; n += 4) {
        float4 a4 = *(const float4*)(A + (size_t)d * DSTATE + n);
        A2[n+0] = a4.x * LOG2E; A2[n+1] = a4.y * LOG2E;
        A2[n+2] = a4.z * LOG2E; A2[n+3] = a4.w * LOG2E;
    }
    float h[DSTATE];
    #pragma unroll
    for (int n = 0; n < DSTATE; ++n) h[n] = 0.f;
    const float Dd = Dv[d];

    const float* up = u  + (size_t)b * SEQLEN * DMODEL + d;
    const float* dp = de + (size_t)b * SEQLEN * DMODEL + d;
    float* yp = y + (size_t)b * SEQLEN * DMODEL + d;

    for (int t = 0; t < SEQLEN; ++t) {
        float dl = dp[(size_t)t * DMODEL];
        float uu = up[(size_t)t * DMODEL];
        float du  = dl * uu;
        float acc = Dd * uu;
        const float* bp = Bm + (size_t)(b * SEQLEN + t) * DSTATE;
        const float* cp = Cm + (size_t)(b * SEQLEN + t) * DSTATE;
        #pragma unroll
        for (int n = 0; n < DSTATE; n += 4) {
            float4 b4 = *(const float4*)(bp + n);
            float4 c4 = *(const float4*)(cp + n);
            h[n+0] = __builtin_amdgcn_exp2f(dl * A2[n+0]) * h[n+0] + du * b4.x;
            h[n+1] = __builtin_amdgcn_exp2f(dl * A2[n+1]) * h[n+1] + du * b4.y;
            h[n+2] = __builtin_amdgcn_exp2f(dl * A2[n+2]) * h[n+2] + du * b4.z;
            h[n+3] = __builtin_amdgcn_exp2f(dl * A2[n+3]) * h[n+3] + du * b4.w;
            acc += h[n+0] * c4.x;
            acc += h[n+1] * c4.y;
            acc += h[n+2] * c4.z;
            acc += h[n+3] * c4.w;
        }
        yp[(size_t)t * DMODEL] = acc;
    }
}

extern "C" void kernel_launch(void* const* d_in, const int* in_sizes, int n_in,
                              void* d_out, int out_size, void* d_ws, size_t ws_size,
                              hipStream_t stream) {
    const float* u  = (const float*)d_in[0];
    const float* de = (const float*)d_in[1];
    const float* A  = (const float*)d_in[2];
    const float* Bm = (const float*)d_in[3];
    const float* Cm = (const float*)d_in[4];
    const float* Dv = (const float*)d_in[5];
    float* y = (float*)d_out;

    auto need = [](int nc) {
        return ((size_t)BATCH * nc * DSTATE * DMODEL +
                (size_t)BATCH * nc * DMODEL) * sizeof(float);
    };

    if (ws_size >= need(128)) {
        constexpr int NC = 128;
        float* ws_h = (float*)d_ws;
        float* ws_d = ws_h + (size_t)BATCH * NC * DSTATE * DMODEL;
        dim3 gridA(DMODEL / BLOCK, NC / 2, BATCH);
        ssm_phaseA_dual<NC><<<gridA, BLOCK, 0, stream>>>(u, de, A, Bm, ws_h, ws_d);
        dim3 gridB((BATCH * DSTATE * DMODEL) / BLOCK, 1, 1);
        ssm_phaseB<NC><<<gridB, BLOCK, 0, stream>>>(A, ws_h, ws_d);
        dim3 gridC(DMODEL / BLOCK, NC, BATCH);
        ssm_phaseC<NC><<<gridC, BLOCK, 0, stream>>>(u, de, A, Bm, Cm, Dv, ws_h, y);
    } else if (ws_size >= need(64)) {
        constexpr int NC = 64;
        float* ws_h = (float*)d_ws;
        float* ws_d = ws_h + (size_t)BATCH * NC * DSTATE * DMODEL;
        dim3 grid(DMODEL / BLOCK, NC, BATCH);
        ssm_phaseA_single<NC><<<grid, BLOCK, 0, stream>>>(u, de, A, Bm, ws_h, ws_d);
        dim3 gridB((BATCH * DSTATE * DMODEL) / BLOCK, 1, 1);
        ssm_phaseB<NC><<<gridB, BLOCK, 0, stream>>>(A, ws_h, ws_d);
        ssm_phaseC<NC><<<grid, BLOCK, 0, stream>>>(u, de, A, Bm, Cm, Dv, ws_h, y);
    } else {
        dim3 grid(DMODEL / BLOCK, 1, BATCH);
        ssm_naive<<<grid, BLOCK, 0, stream>>>(u, de, A, Bm, Cm, Dv, y);
    }
}

// Round 10
// 114.739 us; speedup vs baseline: 1.4966x; 1.0399x over previous
//
#include <hip/hip_runtime.h>

#define BATCH   8
#define SEQLEN  2048
#define DMODEL  1024
#define DSTATE  16
#define BLOCK   256
#define LOG2E   1.4426950408889634f

typedef float v2f __attribute__((ext_vector_type(2)));

// ---------------------------------------------------------------------------
// Phase A: per-(b,d,chunk) local scan from h=0. u/delta slab + B tile staged
// in LDS up front (compiler-proof prefetch); inner loop = packed-f32 math
// (v_pk_mul/v_pk_fma) + hw exp2. Emits h_loc[16] + dsum.
// ---------------------------------------------------------------------------
template<int NC>
__global__ __launch_bounds__(BLOCK, 4) void ssm_phaseA(
    const float* __restrict__ u,  const float* __restrict__ de,
    const float* __restrict__ A,  const float* __restrict__ Bm,
    float* __restrict__ ws_h, float* __restrict__ ws_d)
{
    constexpr int TC = SEQLEN / NC;
    __shared__ __align__(16) float sB[TC * DSTATE];
    __shared__ __align__(16) float sU[TC][BLOCK];
    __shared__ __align__(16) float sD[TC][BLOCK];
    const int tid = threadIdx.x;
    const int d   = blockIdx.x * BLOCK + tid;
    const int c   = blockIdx.y;
    const int b   = blockIdx.z;
    const int t0  = c * TC;
    const int d0b = blockIdx.x * BLOCK;

    if (tid < TC * DSTATE / 4)
        ((float4*)sB)[tid] =
            ((const float4*)(Bm + (size_t)(b * SEQLEN + t0) * DSTATE))[tid];
    {
        const int tr = tid >> 6, c4 = tid & 63;
        #pragma unroll
        for (int k = 0; k < TC; k += 4) {
            ((float4*)&sU[k + tr][0])[c4] =
                ((const float4*)(u  + (size_t)(b * SEQLEN + t0 + k + tr) * DMODEL + d0b))[c4];
            ((float4*)&sD[k + tr][0])[c4] =
                ((const float4*)(de + (size_t)(b * SEQLEN + t0 + k + tr) * DMODEL + d0b))[c4];
        }
    }

    v2f A2[8];
    #pragma unroll
    for (int k = 0; k < 8; k += 2) {
        float4 a4 = *(const float4*)(A + (size_t)d * DSTATE + 2 * k);
        A2[k]   = (v2f){a4.x * LOG2E, a4.y * LOG2E};
        A2[k+1] = (v2f){a4.z * LOG2E, a4.w * LOG2E};
    }
    v2f h[8];
    #pragma unroll
    for (int k = 0; k < 8; ++k) h[k] = (v2f){0.f, 0.f};
    float dsum = 0.f;

    __syncthreads();

    #pragma unroll
    for (int t = 0; t < TC; ++t) {
        const float dl = sD[t][tid];
        const float uu = sU[t][tid];
        dsum += dl;
        const float du = dl * uu;
        const v2f dl2 = (v2f){dl, dl};
        const v2f du2 = (v2f){du, du};
        #pragma unroll
        for (int k = 0; k < 8; ++k) {
            v2f m = dl2 * A2[k];                       // v_pk_mul_f32
            v2f e;
            e.x = __builtin_amdgcn_exp2f(m.x);
            e.y = __builtin_amdgcn_exp2f(m.y);
            v2f bb = *(const v2f*)(sB + t * DSTATE + 2 * k);
            h[k] = e * h[k] + du2 * bb;                // v_pk_mul + v_pk_fma
        }
    }

    float* wh = ws_h + (size_t)(b * NC + c) * DSTATE * DMODEL + d;
    #pragma unroll
    for (int k = 0; k < 8; ++k) {
        wh[(size_t)(2*k)   * DMODEL] = h[k].x;
        wh[(size_t)(2*k+1) * DMODEL] = h[k].y;
    }
    ws_d[(size_t)(b * NC + c) * DMODEL + d] = dsum;
}

// ---------------------------------------------------------------------------
// Phase B: inter-chunk exclusive prefix scan, in place.
// ---------------------------------------------------------------------------
template<int NC>
__global__ __launch_bounds__(BLOCK) void ssm_phaseB(
    const float* __restrict__ A,
    float* __restrict__ ws_h, const float* __restrict__ ws_d)
{
    const int gid = blockIdx.x * BLOCK + threadIdx.x;   // (b, n, d)
    const int d  = gid % DMODEL;
    const int bn = gid / DMODEL;
    const int n  = bn % DSTATE;
    const int b  = bn / DSTATE;

    const float a2 = A[(size_t)d * DSTATE + n] * LOG2E;
    float h = 0.f;
    size_t ih = (size_t)b * NC * DSTATE * DMODEL + (size_t)n * DMODEL + d;
    size_t id = (size_t)b * NC * DMODEL + d;

    #pragma unroll 4
    for (int c = 0; c < NC; ++c) {
        float hl = ws_h[ih];
        float ds = ws_d[id];
        ws_h[ih] = h;                       // exclusive prefix
        h = __builtin_amdgcn_exp2f(a2 * ds) * h + hl;
        ih += (size_t)DSTATE * DMODEL;
        id += DMODEL;
    }
}

// ---------------------------------------------------------------------------
// Phase C: load incoming state, re-scan chunk from LDS slabs with packed-f32
// math, write y (non-temporal).
// ---------------------------------------------------------------------------
template<int NC>
__global__ __launch_bounds__(BLOCK, 4) void ssm_phaseC(
    const float* __restrict__ u,  const float* __restrict__ de,
    const float* __restrict__ A,  const float* __restrict__ Bm,
    const float* __restrict__ Cm, const float* __restrict__ Dv,
    const float* __restrict__ ws_h, float* __restrict__ y)
{
    constexpr int TC = SEQLEN / NC;
    __shared__ __align__(16) float sB[TC * DSTATE];
    __shared__ __align__(16) float sC[TC * DSTATE];
    __shared__ __align__(16) float sU[TC][BLOCK];
    __shared__ __align__(16) float sD[TC][BLOCK];
    const int tid = threadIdx.x;
    const int d   = blockIdx.x * BLOCK + tid;
    const int c   = blockIdx.y;
    const int b   = blockIdx.z;
    const int t0  = c * TC;
    const int d0b = blockIdx.x * BLOCK;

    if (tid < TC * DSTATE / 4)
        ((float4*)sB)[tid] =
            ((const float4*)(Bm + (size_t)(b * SEQLEN + t0) * DSTATE))[tid];
    else if (tid < 2 * (TC * DSTATE / 4))
        ((float4*)sC)[tid - TC*DSTATE/4] =
            ((const float4*)(Cm + (size_t)(b * SEQLEN + t0) * DSTATE))[tid - TC*DSTATE/4];
    {
        const int tr = tid >> 6, c4 = tid & 63;
        #pragma unroll
        for (int k = 0; k < TC; k += 4) {
            ((float4*)&sU[k + tr][0])[c4] =
                ((const float4*)(u  + (size_t)(b * SEQLEN + t0 + k + tr) * DMODEL + d0b))[c4];
            ((float4*)&sD[k + tr][0])[c4] =
                ((const float4*)(de + (size_t)(b * SEQLEN + t0 + k + tr) * DMODEL + d0b))[c4];
        }
    }

    v2f A2[8];
    #pragma unroll
    for (int k = 0; k < 8; k += 2) {
        float4 a4 = *(const float4*)(A + (size_t)d * DSTATE + 2 * k);
        A2[k]   = (v2f){a4.x * LOG2E, a4.y * LOG2E};
        A2[k+1] = (v2f){a4.z * LOG2E, a4.w * LOG2E};
    }

    v2f h[8];
    {
        const float* wh = ws_h + (size_t)(b * NC + c) * DSTATE * DMODEL + d;
        #pragma unroll
        for (int k = 0; k < 8; ++k) {
            h[k].x = wh[(size_t)(2*k)   * DMODEL];
            h[k].y = wh[(size_t)(2*k+1) * DMODEL];
        }
    }
    const float Dd = Dv[d];
    float* yp = y + (size_t)(b * SEQLEN + t0) * DMODEL + d;

    __syncthreads();

    #pragma unroll
    for (int t = 0; t < TC; ++t) {
        const float dl = sD[t][tid];
        const float uu = sU[t][tid];
        const float du = dl * uu;
        const v2f dl2 = (v2f){dl, dl};
        const v2f du2 = (v2f){du, du};
        v2f accv = (v2f){Dd * uu, 0.f};
        #pragma unroll
        for (int k = 0; k < 8; ++k) {
            v2f m = dl2 * A2[k];
            v2f e;
            e.x = __builtin_amdgcn_exp2f(m.x);
            e.y = __builtin_amdgcn_exp2f(m.y);
            v2f bb = *(const v2f*)(sB + t * DSTATE + 2 * k);
            v2f cc = *(const v2f*)(sC + t * DSTATE + 2 * k);
            h[k] = e * h[k] + du2 * bb;
            accv = accv + h[k] * cc;
        }
        __builtin_nontemporal_store(accv.x + accv.y, yp + (size_t)t * DMODEL);
    }
}

// ---------------------------------------------------------------------------
// Fallback: 1 thread per (b,d), full sequential scan. Correct but slow.
// ---------------------------------------------------------------------------
__global__ __launch_bounds__(BLOCK) void ssm_naive(
    const float* __restrict__ u,  const float* __restrict__ de,
    const float* __restrict__ A,  const float* __restrict__ Bm,
    const float* __restrict__ Cm, const float* __restrict__ Dv,
    float* __restrict__ y)
{
    const int tid = threadIdx.x;
    const int d   = blockIdx.x * BLOCK + tid;
    const int b   = blockIdx.z;

    float A2[DSTATE];
    #pragma unroll
    for (int n = 0; n < DSTATE; n += 4) {
        float4 a4 = *(const float4*)(A + (size_t)d * DSTATE + n);
        A2[n+0] = a4.x * LOG2E; A2[n+1] = a4.y * LOG2E;
        A2[n+2] = a4.z * LOG2E; A2[n+3] = a4.w * LOG2E;
    }
    float h[DSTATE];
    #pragma unroll
    for (int n = 0; n < DSTATE; ++n) h[n] = 0.f;
    const float Dd = Dv[d];

    const float* up = u  + (size_t)b * SEQLEN * DMODEL + d;
    const float* dp = de + (size_t)b * SEQLEN * DMODEL + d;
    float* yp = y + (size_t)b * SEQLEN * DMODEL + d;

    for (int t = 0; t < SEQLEN; ++t) {
        float dl = dp[(size_t)t * DMODEL];
        float uu = up[(size_t)t * DMODEL];
        float du  = dl * uu;
        float acc = Dd * uu;
        const float* bp = Bm + (size_t)(b * SEQLEN + t) * DSTATE;
        const float* cp = Cm + (size_t)(b * SEQLEN + t) * DSTATE;
        #pragma unroll
        for (int n = 0; n < DSTATE; n += 4) {
            float4 b4 = *(const float4*)(bp + n);
            float4 c4 = *(const float4*)(cp + n);
            h[n+0] = __builtin_amdgcn_exp2f(dl * A2[n+0]) * h[n+0] + du * b4.x;
            h[n+1] = __builtin_amdgcn_exp2f(dl * A2[n+1]) * h[n+1] + du * b4.y;
            h[n+2] = __builtin_amdgcn_exp2f(dl * A2[n+2]) * h[n+2] + du * b4.z;
            h[n+3] = __builtin_amdgcn_exp2f(dl * A2[n+3]) * h[n+3] + du * b4.w;
            acc += h[n+0] * c4.x;
            acc += h[n+1] * c4.y;
            acc += h[n+2] * c4.z;
            acc += h[n+3] * c4.w;
        }
        yp[(size_t)t * DMODEL] = acc;
    }
}

template<int NC>
static void launch_chunked(const float* u, const float* de, const float* A,
                           const float* Bm, const float* Cm, const float* Dv,
                           float* ws, float* y, hipStream_t stream) {
    float* ws_h = ws;
    float* ws_d = ws_h + (size_t)BATCH * NC * DSTATE * DMODEL;
    dim3 grid(DMODEL / BLOCK, NC, BATCH);
    ssm_phaseA<NC><<<grid, BLOCK, 0, stream>>>(u, de, A, Bm, ws_h, ws_d);
    dim3 gridB((BATCH * DSTATE * DMODEL) / BLOCK, 1, 1);
    ssm_phaseB<NC><<<gridB, BLOCK, 0, stream>>>(A, ws_h, ws_d);
    ssm_phaseC<NC><<<grid, BLOCK, 0, stream>>>(u, de, A, Bm, Cm, Dv, ws_h, y);
}

extern "C" void kernel_launch(void* const* d_in, const int* in_sizes, int n_in,
                              void* d_out, int out_size, void* d_ws, size_t ws_size,
                              hipStream_t stream) {
    const float* u  = (const float*)d_in[0];
    const float* de = (const float*)d_in[1];
    const float* A  = (const float*)d_in[2];
    const float* Bm = (const float*)d_in[3];
    const float* Cm = (const float*)d_in[4];
    const float* Dv = (const float*)d_in[5];
    float* y = (float*)d_out;

    auto need = [](int nc) {
        return ((size_t)BATCH * nc * DSTATE * DMODEL +
                (size_t)BATCH * nc * DMODEL) * sizeof(float);
    };

    if (ws_size >= need(128)) {
        launch_chunked<128>(u, de, A, Bm, Cm, Dv, (float*)d_ws, y, stream);
    } else if (ws_size >= need(64)) {
        launch_chunked<64>(u, de, A, Bm, Cm, Dv, (float*)d_ws, y, stream);
    } else {
        dim3 grid(DMODEL / BLOCK, 1, BATCH);
        ssm_naive<<<grid, BLOCK, 0, stream>>>(u, de, A, Bm, Cm, Dv, y);
    }
}